// Round 6
// baseline (700.478 us; speedup 1.0000x reference)
//
#include <hip/hip_runtime.h>
#include <hip/hip_bf16.h>

static constexpr int C  = 21;
static constexpr int H  = 384;
static constexpr int W  = 384;
static constexpr int HW = H * W;
static constexpr float NCLIQ = 5.0f;

// function-local constexpr taps: exp(-o^2/18), o=-6..6 — folds to immediates
#define GKDEF constexpr float gk[13] = { \
    0.13533528f, 0.24935222f, 0.41111229f, 0.60653066f, 0.80073740f, \
    0.94595947f, 1.00000000f, 0.94595947f, 0.80073740f, 0.60653066f, \
    0.41111229f, 0.24935222f, 0.13533528f }

// unaries (H,W,C) fp32 -> q (C,H,W) fp32
__global__ void k_init(const float* un, float* q) {
    int p = blockIdx.x * blockDim.x + threadIdx.x;
    if (p >= HW) return;
    for (int c = 0; c < C; c++) q[c * HW + p] = un[p * C + c];
}

// bilateral tap weights sw*cw (0 for out-of-range taps) + their sum (= norm)
__global__ void k_wtab(const float* rgb, float* wtab, float* wsum) {
    int p = blockIdx.x * blockDim.x + threadIdx.x;
    if (p >= HW) return;
    int y = p / W, x = p - y * W;
    float r0 = rgb[p * 3 + 0];
    float g0 = rgb[p * 3 + 1];
    float b0 = rgb[p * 3 + 2];
    float s = 0.f;
    int t = 0;
    for (int dy = -2; dy <= 2; dy++) {
        for (int dx = -2; dx <= 2; dx++, t++) {
            int sy = y - dy, sx = x - dx;
            float wv = 0.f;
            if (sy >= 0 && sy < H && sx >= 0 && sx < W) {
                int sp = sy * W + sx;
                float dr = r0 - rgb[sp * 3 + 0];
                float dg = g0 - rgb[sp * 3 + 1];
                float db = b0 - rgb[sp * 3 + 2];
                float sw = expf(-(float)(dy * dy + dx * dx) * (1.0f / 51200.0f));
                float cw = expf(-(dr * dr + dg * dg + db * db) * (1.0f / 18.0f));
                wv = sw * cw;
            }
            wtab[t * HW + p] = wv;
            s += wv;
        }
    }
    wsum[p] = s;   // >= 1 (center tap is exactly 1)
}

// msum[y][x] = indicator(superpixels[0][x][y] in CLIQUE_IDS)  (sp transpose!)
__global__ void k_msum(const int* sp, float* msum) {
    int p = blockIdx.x * blockDim.x + threadIdx.x;
    if (p >= HW) return;
    int y = p / W, x = p - y * W;
    int v = sp[x * W + y];
    msum[p] = (v == 5 || v == 37 || v == 81 || v == 150 || v == 230) ? 1.0f : 0.0f;
}

// M1 = Cm @ Ws,  M2 = Cm @ Wb  (21x21 each)
__global__ void k_mats(const float* Wsp, const float* Wbi, const float* Cm,
                       float* M1, float* M2) {
    int i = blockIdx.x * blockDim.x + threadIdx.x;
    if (i >= C * C) return;
    int c = i / C, k = i - c * C;
    float a1 = 0.f, a2 = 0.f;
    for (int j = 0; j < C; j++) {
        float cm = Cm[c * C + j];
        a1 += cm * Wsp[j * C + k];
        a2 += cm * Wbi[j * C + k];
    }
    M1[i] = a1;
    M2[i] = a2;
}

__global__ void k_softmax(const float* q, float* sm) {
    int p = blockIdx.x * blockDim.x + threadIdx.x;
    if (p >= HW) return;
    float v[C];
    float mx = -1e30f;
    for (int c = 0; c < C; c++) {
        v[c] = q[c * HW + p];
        mx = fmaxf(mx, v[c]);
    }
    float s = 0.f;
    for (int c = 0; c < C; c++) {
        v[c] = expf(v[c] - mx);
        s += v[c];
    }
    float inv = 1.0f / s;
    for (int c = 0; c < C; c++) sm[c * HW + p] = v[c] * inv;
}

// vertical Gaussian pass (zero-padded)
__global__ void k_blurv(const float* in, float* out) {
    GKDEF;
    int g = blockIdx.x * blockDim.x + threadIdx.x;
    if (g >= C * HW) return;
    int c = g / HW, rem = g - c * HW;
    int y = rem / W, x = rem - y * W;
    const float* pl = in + c * HW;
    float a = 0.f;
    for (int o = -6; o <= 6; o++) {
        int sy = y - o;
        if (sy >= 0 && sy < H) a += gk[o + 6] * pl[sy * W + x];
    }
    out[g] = a;
}

// horizontal pass + divide by separable spatial_norm f(y)*f(x)
__global__ void k_blurh(const float* in, float* out) {
    GKDEF;
    int g = blockIdx.x * blockDim.x + threadIdx.x;
    if (g >= C * HW) return;
    int c = g / HW, rem = g - c * HW;
    int y = rem / W, x = rem - y * W;
    const float* row = in + c * HW + y * W;
    float a = 0.f;
    for (int o = -6; o <= 6; o++) {
        int sx = x - o;
        if (sx >= 0 && sx < W) a += gk[o + 6] * row[sx];
    }
    float fy = 0.f, fx = 0.f;
    for (int o = -6; o <= 6; o++) {
        if (y - o >= 0 && y - o < H) fy += gk[o + 6];
        if (x - o >= 0 && x - o < W) fx += gk[o + 6];
    }
    out[g] = a / (fy * fx);   // fy,fx >= 1
}

// bilateral: 25 taps, weight shared across channels; zero-weight taps skipped
__global__ void k_bilateral(const float* sm, const float* wtab,
                            const float* wsum, float* out) {
    int p = blockIdx.x * blockDim.x + threadIdx.x;
    if (p >= HW) return;
    int y = p / W, x = p - y * W;
    float acc[C];
    for (int c = 0; c < C; c++) acc[c] = 0.f;
    int t = 0;
    for (int dy = -2; dy <= 2; dy++) {
        for (int dx = -2; dx <= 2; dx++, t++) {
            float wv = wtab[t * HW + p];
            if (wv != 0.0f) {
                const float* src = sm + (y - dy) * W + (x - dx);
                for (int c = 0; c < C; c++) acc[c] += wv * src[c * HW];
            }
        }
    }
    float inv = 1.0f / wsum[p];
    for (int c = 0; c < C; c++) out[c * HW + p] = acc[c] * inv;
}

// pairwise = M1@spatial + M2@bilateral ; q = u - pairwise + sp_update
__global__ void k_combine(const float* spo, const float* bio,
                          const float* M1, const float* M2,
                          const float* un, const float* msum,
                          const float* loww, const float* highw,
                          float* q) {
    __shared__ float sM1[C * C], sM2[C * C], slow[C], shigh;
    for (int i = threadIdx.x; i < C * C; i += blockDim.x) {
        sM1[i] = M1[i];
        sM2[i] = M2[i];
    }
    if (threadIdx.x < C) slow[threadIdx.x] = loww[threadIdx.x];
    if (threadIdx.x == 0) shigh = highw[0];
    __syncthreads();
    int p = blockIdx.x * blockDim.x + threadIdx.x;
    if (p >= HW) return;
    float acc[C];
    for (int c = 0; c < C; c++) acc[c] = 0.f;
    for (int k = 0; k < C; k++) {
        float s = spo[k * HW + p];
        float b = bio[k * HW + p];
        for (int c = 0; c < C; c++)
            acc[c] += sM1[c * C + k] * s + sM2[c * C + k] * b;
    }
    float ms = msum[p];
    for (int c = 0; c < C; c++) {
        float qo = q[c * HW + p];
        float ft = (ms * qo + (NCLIQ - ms)) / qo;
        float su = slow[c] * ft + shigh * (1.0f - ft);
        q[c * HW + p] = un[p * C + c] - acc[c] + su;
    }
}

// final store: q (C,H,W) fp32 -> out (H,W,C) fp32   [output IS fp32 — the
// half-written-buffer signature of R2/R4/R5 proved bf16 stores were wrong]
__global__ void k_store(const float* q, float* out) {
    int p = blockIdx.x * blockDim.x + threadIdx.x;
    if (p >= HW) return;
    for (int c = 0; c < C; c++)
        out[p * C + c] = q[c * HW + p];
}

extern "C" void kernel_launch(void* const* d_in, const int* in_sizes, int n_in,
                              void* d_out, int out_size, void* d_ws, size_t ws_size,
                              hipStream_t stream) {
    const float* un    = (const float*)d_in[0];
    const float* rgb   = (const float*)d_in[1];
    const int*   sp    = (const int*)d_in[2];
    const float* Wsp   = (const float*)d_in[3];
    const float* Wbi   = (const float*)d_in[4];
    const float* Cm    = (const float*)d_in[5];
    const float* loww  = (const float*)d_in[6];
    const float* highw = (const float*)d_in[7];
    float* out = (float*)d_out;

    // workspace layout (fp32), ~62.4 MiB — proven to fit and execute (R1/R3)
    float* ws   = (float*)d_ws;
    float* q    = ws;                         // C*HW
    float* sm   = q + (size_t)C * HW;         // C*HW
    float* tmp  = sm + (size_t)C * HW;        // C*HW (blurV out / bilateral out)
    float* spo  = tmp + (size_t)C * HW;       // C*HW
    float* wtab = spo + (size_t)C * HW;       // 25*HW
    float* wsum = wtab + (size_t)25 * HW;     // HW
    float* msum = wsum + HW;                  // HW
    float* M1   = msum + HW;                  // C*C
    float* M2   = M1 + C * C;                 // C*C

    dim3 blk(256);
    dim3 gpix((HW + 255) / 256);
    dim3 gel((C * HW + 255) / 256);
    dim3 gmat((C * C + 255) / 256);

    k_init<<<gpix, blk, 0, stream>>>(un, q);
    k_wtab<<<gpix, blk, 0, stream>>>(rgb, wtab, wsum);
    k_msum<<<gpix, blk, 0, stream>>>(sp, msum);
    k_mats<<<gmat, blk, 0, stream>>>(Wsp, Wbi, Cm, M1, M2);

    for (int it = 0; it < 5; it++) {
        k_softmax<<<gpix, blk, 0, stream>>>(q, sm);
        k_blurv<<<gel, blk, 0, stream>>>(sm, tmp);
        k_blurh<<<gel, blk, 0, stream>>>(tmp, spo);
        k_bilateral<<<gpix, blk, 0, stream>>>(sm, wtab, wsum, tmp);
        k_combine<<<gpix, blk, 0, stream>>>(spo, tmp, M1, M2, un, msum,
                                            loww, highw, q);
    }
    k_store<<<gpix, blk, 0, stream>>>(q, out);
}

// Round 7
// 584.178 us; speedup vs baseline: 1.1991x; 1.1991x over previous
//
#include <hip/hip_runtime.h>
#include <hip/hip_bf16.h>

static constexpr int C  = 21;
static constexpr int H  = 384;
static constexpr int W  = 384;
static constexpr int HW = H * W;
static constexpr float NCLIQ = 5.0f;

// function-local constexpr taps: exp(-o^2/18), o=-6..6 — folds to immediates
#define GKDEF constexpr float gk[13] = { \
    0.13533528f, 0.24935222f, 0.41111229f, 0.60653066f, 0.80073740f, \
    0.94595947f, 1.00000000f, 0.94595947f, 0.80073740f, 0.60653066f, \
    0.41111229f, 0.24935222f, 0.13533528f }

// ---- prep: init q + bilateral weight table + clique mask (one pass) --------
__global__ void k_prep(const float* __restrict__ un, const float* __restrict__ rgb,
                       const int* __restrict__ sp,
                       float* __restrict__ q, float* __restrict__ wtab,
                       float* __restrict__ wsum, float* __restrict__ msum) {
    int p = blockIdx.x * blockDim.x + threadIdx.x;
    if (p >= HW) return;
    int y = p / W, x = p - y * W;

    // q init (C,H,W) <- unaries (H,W,C)
    for (int c = 0; c < C; c++) q[c * HW + p] = un[p * C + c];

    // bilateral tap weights
    float r0 = rgb[p * 3 + 0];
    float g0 = rgb[p * 3 + 1];
    float b0 = rgb[p * 3 + 2];
    float s = 0.f;
    int t = 0;
    for (int dy = -2; dy <= 2; dy++) {
        for (int dx = -2; dx <= 2; dx++, t++) {
            int sy = y - dy, sx = x - dx;
            float wv = 0.f;
            if (sy >= 0 && sy < H && sx >= 0 && sx < W) {
                int o = sy * W + sx;
                float dr = r0 - rgb[o * 3 + 0];
                float dg = g0 - rgb[o * 3 + 1];
                float db = b0 - rgb[o * 3 + 2];
                float sw = expf(-(float)(dy * dy + dx * dx) * (1.0f / 51200.0f));
                float cw = expf(-(dr * dr + dg * dg + db * db) * (1.0f / 18.0f));
                wv = sw * cw;
            }
            wtab[t * HW + p] = wv;
            s += wv;
        }
    }
    wsum[p] = s;   // >= 1 (center tap is exactly 1)

    // clique mask (sp_map is transposed: sp[x][y])
    int v = sp[x * W + y];
    msum[p] = (v == 5 || v == 37 || v == 81 || v == 150 || v == 230) ? 1.0f : 0.0f;
}

// M1 = Cm @ Ws,  M2 = Cm @ Wb  (21x21 each)
__global__ void k_mats(const float* __restrict__ Wsp, const float* __restrict__ Wbi,
                       const float* __restrict__ Cm,
                       float* __restrict__ M1, float* __restrict__ M2) {
    int i = blockIdx.x * blockDim.x + threadIdx.x;
    if (i >= C * C) return;
    int c = i / C, k = i - c * C;
    float a1 = 0.f, a2 = 0.f;
    for (int j = 0; j < C; j++) {
        float cm = Cm[c * C + j];
        a1 += cm * Wsp[j * C + k];
        a2 += cm * Wbi[j * C + k];
    }
    M1[i] = a1;
    M2[i] = a2;
}

// ---- per-iteration ---------------------------------------------------------

__global__ void k_softmax(const float* __restrict__ q, float* __restrict__ sm) {
    int p = blockIdx.x * blockDim.x + threadIdx.x;
    if (p >= HW) return;
    float v[C];
    float mx = -1e30f;
    for (int c = 0; c < C; c++) {
        v[c] = q[c * HW + p];
        mx = fmaxf(mx, v[c]);
    }
    float s = 0.f;
    for (int c = 0; c < C; c++) {
        v[c] = expf(v[c] - mx);
        s += v[c];
    }
    float inv = 1.0f / s;
    for (int c = 0; c < C; c++) sm[c * HW + p] = v[c] * inv;
}

// vertical Gaussian pass (zero-padded)
__global__ void k_blurv(const float* __restrict__ in, float* __restrict__ out) {
    GKDEF;
    int g = blockIdx.x * blockDim.x + threadIdx.x;
    if (g >= C * HW) return;
    int c = g / HW, rem = g - c * HW;
    int y = rem / W, x = rem - y * W;
    const float* pl = in + c * HW;
    float a = 0.f;
    for (int o = -6; o <= 6; o++) {
        int sy = y - o;
        if (sy >= 0 && sy < H) a += gk[o + 6] * pl[sy * W + x];
    }
    out[g] = a;
}

// fused: horizontal blur (+sep norm) + bilateral (+norm) + CxC combine +
// superpixel update; writes q (iters 0..3) or final output (iter 4)
__global__ __launch_bounds__(256)
void k_fused(const float* __restrict__ sm, const float* __restrict__ tmp,
             const float* __restrict__ wtab, const float* __restrict__ wsum,
             const float* __restrict__ msum,
             const float* __restrict__ M1, const float* __restrict__ M2,
             const float* __restrict__ un,
             const float* __restrict__ loww, const float* __restrict__ highw,
             float* __restrict__ q, float* __restrict__ finalout) {
    GKDEF;
    __shared__ float sM1[C * C], sM2[C * C], slow[C], shigh;
    for (int i = threadIdx.x; i < C * C; i += 256) {
        sM1[i] = M1[i];
        sM2[i] = M2[i];
    }
    if (threadIdx.x < C) slow[threadIdx.x] = loww[threadIdx.x];
    if (threadIdx.x == 0) shigh = highw[0];
    __syncthreads();

    int p = blockIdx.x * 256 + threadIdx.x;   // HW % 256 == 0
    int y = p / W, x = p - y * W;

    // ---- spatial: horizontal 13-tap over blurv output, all channels ----
    float acc_sp[C];
    for (int c = 0; c < C; c++) acc_sp[c] = 0.f;
    {
        const float* base = tmp + y * W;
        for (int o = -6; o <= 6; o++) {
            int sx = x - o;
            if (sx >= 0 && sx < W) {
                float g = gk[o + 6];
                const float* col = base + sx;
                for (int c = 0; c < C; c++) acc_sp[c] += g * col[c * HW];
            }
        }
    }
    // separable spatial norm
    float fy = 0.f, fxn = 0.f;
    for (int o = -6; o <= 6; o++) {
        if (y - o >= 0 && y - o < H) fy += gk[o + 6];
        if (x - o >= 0 && x - o < W) fxn += gk[o + 6];
    }
    float spnorm = 1.0f / (fy * fxn);

    // ---- bilateral: 25 taps, weight shared across channels ----
    float acc_bi[C];
    for (int c = 0; c < C; c++) acc_bi[c] = 0.f;
    int t = 0;
    for (int dy = -2; dy <= 2; dy++) {
        for (int dx = -2; dx <= 2; dx++, t++) {
            float wv = wtab[t * HW + p];
            if (wv != 0.0f) {
                const float* src = sm + (y - dy) * W + (x - dx);
                for (int c = 0; c < C; c++) acc_bi[c] += wv * src[c * HW];
            }
        }
    }
    float binorm = 1.0f / wsum[p];

    // ---- pairwise = M1 @ spatial + M2 @ bilateral ----
    float acc[C];
    for (int c = 0; c < C; c++) acc[c] = 0.f;
    for (int k = 0; k < C; k++) {
        float s = acc_sp[k] * spnorm;
        float b = acc_bi[k] * binorm;
        for (int c = 0; c < C; c++)
            acc[c] += sM1[c * C + k] * s + sM2[c * C + k] * b;
    }

    // ---- superpixel closed form + q update ----
    float ms = msum[p];
    for (int c = 0; c < C; c++) {
        float qo = q[c * HW + p];
        float ft = (ms * qo + (NCLIQ - ms)) / qo;
        float su = slow[c] * ft + shigh * (1.0f - ft);
        float qn = un[p * C + c] - acc[c] + su;
        if (finalout)
            finalout[p * C + c] = qn;     // (H,W,C) fp32
        else
            q[c * HW + p] = qn;
    }
}

// ---- launch -----------------------------------------------------------------

extern "C" void kernel_launch(void* const* d_in, const int* in_sizes, int n_in,
                              void* d_out, int out_size, void* d_ws, size_t ws_size,
                              hipStream_t stream) {
    const float* un    = (const float*)d_in[0];
    const float* rgb   = (const float*)d_in[1];
    const int*   sp    = (const int*)d_in[2];
    const float* Wsp   = (const float*)d_in[3];
    const float* Wbi   = (const float*)d_in[4];
    const float* Cm    = (const float*)d_in[5];
    const float* loww  = (const float*)d_in[6];
    const float* highw = (const float*)d_in[7];
    float* out = (float*)d_out;

    // workspace layout (fp32), ~53 MB
    float* ws   = (float*)d_ws;
    float* q    = ws;                         // C*HW
    float* sm   = q + (size_t)C * HW;         // C*HW
    float* tmp  = sm + (size_t)C * HW;        // C*HW (blurv out)
    float* wtab = tmp + (size_t)C * HW;       // 25*HW
    float* wsum = wtab + (size_t)25 * HW;     // HW
    float* msum = wsum + HW;                  // HW
    float* M1   = msum + HW;                  // C*C
    float* M2   = M1 + C * C;                 // C*C

    dim3 blk(256);
    dim3 gpix(HW / 256);          // 576
    dim3 gel((C * HW) / 256);     // 12096
    dim3 gmat((C * C + 255) / 256);

    k_prep<<<gpix, blk, 0, stream>>>(un, rgb, sp, q, wtab, wsum, msum);
    k_mats<<<gmat, blk, 0, stream>>>(Wsp, Wbi, Cm, M1, M2);

    for (int it = 0; it < 5; it++) {
        k_softmax<<<gpix, blk, 0, stream>>>(q, sm);
        k_blurv<<<gel, blk, 0, stream>>>(sm, tmp);
        k_fused<<<gpix, blk, 0, stream>>>(sm, tmp, wtab, wsum, msum, M1, M2,
                                          un, loww, highw, q,
                                          (it == 4) ? out : (float*)nullptr);
    }
}

// Round 8
// 572.884 us; speedup vs baseline: 1.2227x; 1.0197x over previous
//
#include <hip/hip_runtime.h>
#include <hip/hip_bf16.h>

static constexpr int C  = 21;
static constexpr int H  = 384;
static constexpr int W  = 384;
static constexpr int HW = H * W;
static constexpr float NCLIQ = 5.0f;

// function-local constexpr taps: exp(-o^2/18), o=-6..6 — folds to immediates
#define GKDEF constexpr float gk[13] = { \
    0.13533528f, 0.24935222f, 0.41111229f, 0.60653066f, 0.80073740f, \
    0.94595947f, 1.00000000f, 0.94595947f, 0.80073740f, 0.60653066f, \
    0.41111229f, 0.24935222f, 0.13533528f }

// ---- prep: init q + initial softmax + bilateral weights + clique mask ------
__global__ void k_prep(const float* __restrict__ un, const float* __restrict__ rgb,
                       const int* __restrict__ sp,
                       float* __restrict__ q, float* __restrict__ sm,
                       float* __restrict__ wtab, float* __restrict__ wsum,
                       float* __restrict__ msum) {
    int p = blockIdx.x * blockDim.x + threadIdx.x;
    if (p >= HW) return;
    int y = p / W, x = p - y * W;

    // q init (C,H,W) <- unaries (H,W,C), plus softmax(q) for iteration 0
    float v[C];
    float mx = -1e30f;
    for (int c = 0; c < C; c++) {
        v[c] = un[p * C + c];
        q[c * HW + p] = v[c];
        mx = fmaxf(mx, v[c]);
    }
    float ssum = 0.f;
    for (int c = 0; c < C; c++) {
        v[c] = expf(v[c] - mx);
        ssum += v[c];
    }
    float sinv = 1.0f / ssum;
    for (int c = 0; c < C; c++) sm[c * HW + p] = v[c] * sinv;

    // bilateral tap weights
    float r0 = rgb[p * 3 + 0];
    float g0 = rgb[p * 3 + 1];
    float b0 = rgb[p * 3 + 2];
    float s = 0.f;
    int t = 0;
    for (int dy = -2; dy <= 2; dy++) {
        for (int dx = -2; dx <= 2; dx++, t++) {
            int sy = y - dy, sx = x - dx;
            float wv = 0.f;
            if (sy >= 0 && sy < H && sx >= 0 && sx < W) {
                int o = sy * W + sx;
                float dr = r0 - rgb[o * 3 + 0];
                float dg = g0 - rgb[o * 3 + 1];
                float db = b0 - rgb[o * 3 + 2];
                float sw = expf(-(float)(dy * dy + dx * dx) * (1.0f / 51200.0f));
                float cw = expf(-(dr * dr + dg * dg + db * db) * (1.0f / 18.0f));
                wv = sw * cw;
            }
            wtab[t * HW + p] = wv;
            s += wv;
        }
    }
    wsum[p] = s;   // >= 1 (center tap is exactly 1)

    // clique mask (sp_map is transposed: sp[x][y])
    int vv = sp[x * W + y];
    msum[p] = (vv == 5 || vv == 37 || vv == 81 || vv == 150 || vv == 230) ? 1.0f : 0.0f;
}

// M1 = Cm @ Ws,  M2 = Cm @ Wb  (21x21 each)
__global__ void k_mats(const float* __restrict__ Wsp, const float* __restrict__ Wbi,
                       const float* __restrict__ Cm,
                       float* __restrict__ M1, float* __restrict__ M2) {
    int i = blockIdx.x * blockDim.x + threadIdx.x;
    if (i >= C * C) return;
    int c = i / C, k = i - c * C;
    float a1 = 0.f, a2 = 0.f;
    for (int j = 0; j < C; j++) {
        float cm = Cm[c * C + j];
        a1 += cm * Wsp[j * C + k];
        a2 += cm * Wbi[j * C + k];
    }
    M1[i] = a1;
    M2[i] = a2;
}

// vertical Gaussian pass (zero-padded)
__global__ void k_blurv(const float* __restrict__ in, float* __restrict__ out) {
    GKDEF;
    int g = blockIdx.x * blockDim.x + threadIdx.x;
    if (g >= C * HW) return;
    int c = g / HW, rem = g - c * HW;
    int y = rem / W, x = rem - y * W;
    const float* pl = in + c * HW;
    float a = 0.f;
    for (int o = -6; o <= 6; o++) {
        int sy = y - o;
        if (sy >= 0 && sy < H) a += gk[o + 6] * pl[sy * W + x];
    }
    out[g] = a;
}

// fused: 4 threads per pixel (channel groups {6,5,5,5}); horizontal blur +
// bilateral + LDS exchange + CxC combine + superpixel update + next softmax
__global__ __launch_bounds__(256)
void k_fused(const float* __restrict__ sm, const float* __restrict__ tmp,
             const float* __restrict__ wtab, const float* __restrict__ wsum,
             const float* __restrict__ msum,
             const float* __restrict__ M1, const float* __restrict__ M2,
             const float* __restrict__ un,
             const float* __restrict__ loww, const float* __restrict__ highw,
             float* __restrict__ q, float* __restrict__ smout,
             float* __restrict__ finalout) {
    GKDEF;
    __shared__ float sM1[C * C], sM2[C * C], slow[C], shigh;
    __shared__ float sS[64 * C], sB[64 * C];   // per-pixel exchange
    for (int i = threadIdx.x; i < C * C; i += 256) {
        sM1[i] = M1[i];
        sM2[i] = M2[i];
    }
    if (threadIdx.x < C) slow[threadIdx.x] = loww[threadIdx.x];
    if (threadIdx.x == 0) shigh = highw[0];

    int sub = threadIdx.x & 3;                 // channel group
    int lp  = threadIdx.x >> 2;                // local pixel 0..63
    int p   = blockIdx.x * 64 + lp;            // HW % 64 == 0
    int y = p / W, x = p - y * W;
    int m1 = (sub > 0) ? 1 : 0;
    int kb = sub * 5 + m1;                     // {0,6,11,16}
    int kn = 6 - m1;                           // {6,5,5,5}

    // ---- spatial: horizontal 13-tap over blurv output, own channels ----
    float asp[6], abi[6];
    for (int j = 0; j < 6; j++) { asp[j] = 0.f; abi[j] = 0.f; }
    {
        const float* base = tmp + y * W;
        for (int o = -6; o <= 6; o++) {
            int sx = x - o;
            if ((unsigned)sx < (unsigned)W) {
                float g = gk[o + 6];
                for (int j = 0; j < 6; j++)
                    if (j < kn) asp[j] += g * base[(kb + j) * HW + sx];
            }
        }
    }
    // ---- bilateral: 25 taps, weight shared across channels ----
    {
        int t = 0;
        for (int dy = -2; dy <= 2; dy++) {
            for (int dx = -2; dx <= 2; dx++, t++) {
                float wv = wtab[t * HW + p];
                if (wv != 0.0f) {
                    const float* src = sm + (y - dy) * W + (x - dx);
                    for (int j = 0; j < 6; j++)
                        if (j < kn) abi[j] += wv * src[(kb + j) * HW];
                }
            }
        }
    }
    // norms
    float fy = 0.f, fxn = 0.f;
    for (int o = -6; o <= 6; o++) {
        if (y - o >= 0 && y - o < H) fy += gk[o + 6];
        if (x - o >= 0 && x - o < W) fxn += gk[o + 6];
    }
    float spnorm = 1.0f / (fy * fxn);
    float binorm = 1.0f / wsum[p];

    // exchange normalized s/b vectors through LDS
    for (int j = 0; j < 6; j++)
        if (j < kn) {
            sS[lp * C + kb + j] = asp[j] * spnorm;
            sB[lp * C + kb + j] = abi[j] * binorm;
        }
    __syncthreads();

    // ---- pairwise = M1 @ spatial + M2 @ bilateral  (own output channels) ----
    float acc[6];
    for (int j = 0; j < 6; j++) acc[j] = 0.f;
    for (int k = 0; k < C; k++) {
        float s = sS[lp * C + k];
        float b = sB[lp * C + k];
        for (int j = 0; j < 6; j++)
            if (j < kn) acc[j] += sM1[(kb + j) * C + k] * s + sM2[(kb + j) * C + k] * b;
    }

    // ---- superpixel closed form + q update ----
    float ms = msum[p];
    float qn[6];
    for (int j = 0; j < 6; j++)
        if (j < kn) {
            int c = kb + j;
            float qo = q[c * HW + p];
            float ft = (ms * qo + (NCLIQ - ms)) / qo;
            float su = slow[c] * ft + shigh * (1.0f - ft);
            qn[j] = un[p * C + c] - acc[j] + su;
        }

    if (finalout) {   // uniform branch: last iteration, no softmax needed
        for (int j = 0; j < 6; j++)
            if (j < kn) finalout[p * C + kb + j] = qn[j];
        return;
    }

    // ---- in-kernel softmax of qn -> smout (and store q) ----
    __syncthreads();                       // all matmul LDS reads done
    for (int j = 0; j < 6; j++)
        if (j < kn) sS[lp * C + kb + j] = qn[j];
    __syncthreads();
    float mx = -1e30f;
    for (int k = 0; k < C; k++) mx = fmaxf(mx, sS[lp * C + k]);
    float e[6];
    for (int j = 0; j < 6; j++)
        if (j < kn) {
            e[j] = expf(qn[j] - mx);
            sB[lp * C + kb + j] = e[j];
        }
    __syncthreads();
    float ssum = 0.f;
    for (int k = 0; k < C; k++) ssum += sB[lp * C + k];
    float sinv = 1.0f / ssum;
    for (int j = 0; j < 6; j++)
        if (j < kn) {
            int c = kb + j;
            q[c * HW + p] = qn[j];
            smout[c * HW + p] = e[j] * sinv;
        }
}

// ---- launch -----------------------------------------------------------------

extern "C" void kernel_launch(void* const* d_in, const int* in_sizes, int n_in,
                              void* d_out, int out_size, void* d_ws, size_t ws_size,
                              hipStream_t stream) {
    const float* un    = (const float*)d_in[0];
    const float* rgb   = (const float*)d_in[1];
    const int*   sp    = (const int*)d_in[2];
    const float* Wsp   = (const float*)d_in[3];
    const float* Wbi   = (const float*)d_in[4];
    const float* Cm    = (const float*)d_in[5];
    const float* loww  = (const float*)d_in[6];
    const float* highw = (const float*)d_in[7];
    float* out = (float*)d_out;

    // workspace layout (fp32), ~53 MB (R7-proven size)
    float* ws   = (float*)d_ws;
    float* q    = ws;                         // C*HW
    float* sm   = q + (size_t)C * HW;         // C*HW
    float* tmp  = sm + (size_t)C * HW;        // C*HW (blurv out)
    float* wtab = tmp + (size_t)C * HW;       // 25*HW
    float* wsum = wtab + (size_t)25 * HW;     // HW
    float* msum = wsum + HW;                  // HW
    float* M1   = msum + HW;                  // C*C
    float* M2   = M1 + C * C;                 // C*C

    dim3 blk(256);
    dim3 gpix(HW / 256);            // 576
    dim3 gel((C * HW) / 256);       // 12096
    dim3 gfuse(HW / 64);            // 2304 blocks, 4 threads/pixel
    dim3 gmat((C * C + 255) / 256);

    k_prep<<<gpix, blk, 0, stream>>>(un, rgb, sp, q, sm, wtab, wsum, msum);
    k_mats<<<gmat, blk, 0, stream>>>(Wsp, Wbi, Cm, M1, M2);

    for (int it = 0; it < 5; it++) {
        k_blurv<<<gel, blk, 0, stream>>>(sm, tmp);
        k_fused<<<gfuse, blk, 0, stream>>>(sm, tmp, wtab, wsum, msum, M1, M2,
                                           un, loww, highw, q, sm,
                                           (it == 4) ? out : (float*)nullptr);
    }
}

// Round 9
// 467.001 us; speedup vs baseline: 1.5000x; 1.2267x over previous
//
#include <hip/hip_runtime.h>
#include <hip/hip_bf16.h>

static constexpr int C  = 21;
static constexpr int H  = 384;
static constexpr int W  = 384;
static constexpr int HW = H * W;
static constexpr float NCLIQ = 5.0f;

typedef unsigned short u16;

// function-local constexpr taps: exp(-o^2/18), o=-6..6 — folds to immediates
#define GKDEF constexpr float gk[13] = { \
    0.13533528f, 0.24935222f, 0.41111229f, 0.60653066f, 0.80073740f, \
    0.94595947f, 1.00000000f, 0.94595947f, 0.80073740f, 0.60653066f, \
    0.41111229f, 0.24935222f, 0.13533528f }

__device__ __forceinline__ float bfu2f(u16 u) {
    return __uint_as_float(((unsigned)u) << 16);
}
__device__ __forceinline__ u16 f2bfu(float f) {
    unsigned x = __float_as_uint(f);
    return (u16)((x + 0x7FFF + ((x >> 16) & 1)) >> 16);   // RNE; inputs finite
}

// ---- prep: q init (planar) + bilateral weight table (bf16) + clique mask ---
__global__ __launch_bounds__(256)
void k_prep(const float* __restrict__ un, const float* __restrict__ rgb,
            const int* __restrict__ sp,
            float* __restrict__ q, u16* __restrict__ wtab,
            float* __restrict__ msum) {
    int p = blockIdx.x * 256 + threadIdx.x;     // HW % 256 == 0
    int y = p / W, x = p - y * W;

    for (int c = 0; c < C; c++) q[c * HW + p] = un[p * C + c];

    float r0 = rgb[p * 3 + 0];
    float g0 = rgb[p * 3 + 1];
    float b0 = rgb[p * 3 + 2];
    int t = 0;
    for (int dy = -2; dy <= 2; dy++) {
        for (int dx = -2; dx <= 2; dx++, t++) {
            int sy = y - dy, sx = x - dx;
            float wv = 0.f;
            if (sy >= 0 && sy < H && sx >= 0 && sx < W) {
                int o = sy * W + sx;
                float dr = r0 - rgb[o * 3 + 0];
                float dg = g0 - rgb[o * 3 + 1];
                float db = b0 - rgb[o * 3 + 2];
                wv = expf(-(float)(dy * dy + dx * dx) * (1.0f / 51200.0f)) *
                     expf(-(dr * dr + dg * dg + db * db) * (1.0f / 18.0f));
            }
            wtab[(size_t)t * HW + p] = f2bfu(wv);
        }
    }
    int vv = sp[x * W + y];   // sp_map is transposed: sp[x][y]
    msum[p] = (vv == 5 || vv == 37 || vv == 81 || vv == 150 || vv == 230) ? 1.0f : 0.0f;
}

// M1 = Cm @ Ws,  M2 = Cm @ Wb
__global__ void k_mats(const float* __restrict__ Wsp, const float* __restrict__ Wbi,
                       const float* __restrict__ Cm,
                       float* __restrict__ M1, float* __restrict__ M2) {
    int i = blockIdx.x * blockDim.x + threadIdx.x;
    if (i >= C * C) return;
    int c = i / C, k = i - c * C;
    float a1 = 0.f, a2 = 0.f;
    for (int j = 0; j < C; j++) {
        float cm = Cm[c * C + j];
        a1 += cm * Wsp[j * C + k];
        a2 += cm * Wbi[j * C + k];
    }
    M1[i] = a1;
    M2[i] = a2;
}

// softmax(q) then t1 = M1@sm, t2 = M2@sm  (filters commute with the matmuls:
// blur/bilateral are channel-diagonal with channel-independent weights)
__global__ __launch_bounds__(256)
void k_S(const float* __restrict__ q, const float* __restrict__ M1,
         const float* __restrict__ M2,
         float* __restrict__ t1, float* __restrict__ t2) {
    __shared__ float sM1[C * C], sM2[C * C];
    for (int i = threadIdx.x; i < C * C; i += 256) {
        sM1[i] = M1[i];
        sM2[i] = M2[i];
    }
    __syncthreads();
    int p = blockIdx.x * 256 + threadIdx.x;
    float v[C];
    float mx = -1e30f;
    for (int c = 0; c < C; c++) {
        v[c] = q[c * HW + p];
        mx = fmaxf(mx, v[c]);
    }
    float s = 0.f;
    for (int c = 0; c < C; c++) {
        v[c] = expf(v[c] - mx);
        s += v[c];
    }
    float inv = 1.0f / s;
    float a1[C], a2[C];
    for (int c = 0; c < C; c++) { a1[c] = 0.f; a2[c] = 0.f; }
    for (int k = 0; k < C; k++) {
        float sv = v[k] * inv;
        for (int c = 0; c < C; c++) {
            a1[c] += sM1[c * C + k] * sv;
            a2[c] += sM2[c * C + k] * sv;
        }
    }
    for (int c = 0; c < C; c++) {
        t1[c * HW + p] = a1[c];
        t2[c * HW + p] = a2[c];
    }
}

// vertical blur, channel-parallel, 4 px/thread, float4 loads
__global__ __launch_bounds__(256)
void k_V(const float* __restrict__ t1, float* __restrict__ tv) {
    GKDEF;
    int gid = blockIdx.x * 256 + threadIdx.x;   // over C*HW/4
    int c = gid / (HW / 4), g = gid - c * (HW / 4);
    int p4 = g * 4;
    int y = p4 / W, x4 = p4 - y * W;
    const float* pl = t1 + (size_t)c * HW;
    float a0 = 0.f, a1 = 0.f, a2 = 0.f, a3 = 0.f;
    for (int o = -6; o <= 6; o++) {
        int sy = y - o;
        if (sy >= 0 && sy < H) {
            float4 vv = *(const float4*)(pl + sy * W + x4);
            float g_ = gk[o + 6];
            a0 += g_ * vv.x; a1 += g_ * vv.y; a2 += g_ * vv.z; a3 += g_ * vv.w;
        }
    }
    float4 r; r.x = a0; r.y = a1; r.z = a2; r.w = a3;
    *(float4*)(tv + (size_t)c * HW + p4) = r;
}

// horizontal blur + bilateral + norms + update; channel-parallel, 4 px/thread
__global__ __launch_bounds__(256)
void k_F(const float* __restrict__ tv, const float* __restrict__ t2,
         const u16* __restrict__ wtab, const float* __restrict__ msum,
         const float* __restrict__ un,
         const float* __restrict__ loww, const float* __restrict__ highw,
         float* __restrict__ q) {
    GKDEF;
    int gid = blockIdx.x * 256 + threadIdx.x;   // over C*HW/4
    int c = gid / (HW / 4), g = gid - c * (HW / 4);
    int p4 = g * 4;
    int y = p4 / W, x4 = p4 - y * W;

    // ---- horizontal 13-tap blur of tv (register-shifted window) ----
    float f[20];
    {
        const float* row = tv + (size_t)c * HW + y * W;
        for (int i = 0; i < 5; i++) {
            int bx = x4 - 8 + 4 * i;
            int bc = min(max(bx, 0), W - 4);    // clamped loads; bad slots zeroed below
            float4 vv = *(const float4*)(row + bc);
            f[4 * i + 0] = vv.x; f[4 * i + 1] = vv.y;
            f[4 * i + 2] = vv.z; f[4 * i + 3] = vv.w;
        }
        for (int i = 0; i < 20; i++) {
            int sx = x4 - 8 + i;
            if (sx < 0 || sx >= W) f[i] = 0.f;  // exactly the clamp-shifted slots
        }
    }
    float sp_[4];
    for (int j = 0; j < 4; j++) {
        float a = 0.f;
        for (int o = -6; o <= 6; o++) a += gk[o + 6] * f[j - o + 8];
        sp_[j] = a;
    }
    // separable spatial norm
    float fy = 0.f, fx[4] = {0.f, 0.f, 0.f, 0.f};
    for (int o = -6; o <= 6; o++) {
        int ty = y - o;
        if (ty >= 0 && ty < H) fy += gk[o + 6];
        for (int j = 0; j < 4; j++) {
            int tx = x4 + j - o;
            if (tx >= 0 && tx < W) fx[j] += gk[o + 6];
        }
    }

    // ---- bilateral over t2 (weights bf16; OOB taps have weight 0) ----
    float bi[4] = {0.f, 0.f, 0.f, 0.f}, wsv[4] = {0.f, 0.f, 0.f, 0.f};
    const float* t2p = t2 + (size_t)c * HW;
    int t = 0;
    for (int dy = -2; dy <= 2; dy++) {
        int sy = min(max(y - dy, 0), H - 1);    // clamped; OOB rows weight 0
        const float* row = t2p + sy * W;
        float r[12];
        for (int i = 0; i < 3; i++) {
            int bx = x4 - 4 + 4 * i;
            int bc = min(max(bx, 0), W - 4);    // clamped; OOB cols weight 0
            float4 vv = *(const float4*)(row + bc);
            r[4 * i + 0] = vv.x; r[4 * i + 1] = vv.y;
            r[4 * i + 2] = vv.z; r[4 * i + 3] = vv.w;
        }
        for (int dx = -2; dx <= 2; dx++, t++) {
            ushort4 wu = *(const ushort4*)(wtab + (size_t)t * HW + p4);
            float w0 = bfu2f(wu.x), w1 = bfu2f(wu.y);
            float w2 = bfu2f(wu.z), w3 = bfu2f(wu.w);
            wsv[0] += w0; wsv[1] += w1; wsv[2] += w2; wsv[3] += w3;
            bi[0] += w0 * r[0 - dx + 4];
            bi[1] += w1 * r[1 - dx + 4];
            bi[2] += w2 * r[2 - dx + 4];
            bi[3] += w3 * r[3 - dx + 4];
        }
    }

    // ---- update: q = un - pairwise + superpixel closed form ----
    float lc = loww[c], hw_ = highw[0];
    float4 msv = *(const float4*)(msum + p4);
    float msa[4] = {msv.x, msv.y, msv.z, msv.w};
    float* qp = q + (size_t)c * HW + p4;
    float4 qo4 = *(const float4*)qp;
    float qoa[4] = {qo4.x, qo4.y, qo4.z, qo4.w};
    float outv[4];
    for (int j = 0; j < 4; j++) {
        float pw = sp_[j] / (fy * fx[j]) + bi[j] / wsv[j];
        float qo = qoa[j];
        float ft = (msa[j] * qo + (NCLIQ - msa[j])) / qo;
        float su = lc * ft + hw_ * (1.0f - ft);
        outv[j] = un[(p4 + j) * C + c] - pw + su;
    }
    float4 res; res.x = outv[0]; res.y = outv[1]; res.z = outv[2]; res.w = outv[3];
    *(float4*)qp = res;
}

// final transpose: q (C,H,W) -> out (H,W,C), LDS-staged, coalesced both sides
__global__ __launch_bounds__(256)
void k_store(const float* __restrict__ q, float* __restrict__ out) {
    __shared__ float l[256 * C];
    int p0 = blockIdx.x * 256;
    for (int c = 0; c < C; c++)
        l[threadIdx.x * C + c] = q[c * HW + p0 + threadIdx.x];
    __syncthreads();
    float* dst = out + (size_t)p0 * C;
    for (int i = threadIdx.x; i < 256 * C; i += 256) dst[i] = l[i];
}

// ---- launch -----------------------------------------------------------------

extern "C" void kernel_launch(void* const* d_in, const int* in_sizes, int n_in,
                              void* d_out, int out_size, void* d_ws, size_t ws_size,
                              hipStream_t stream) {
    const float* un    = (const float*)d_in[0];
    const float* rgb   = (const float*)d_in[1];
    const int*   sp    = (const int*)d_in[2];
    const float* Wsp   = (const float*)d_in[3];
    const float* Wbi   = (const float*)d_in[4];
    const float* Cm    = (const float*)d_in[5];
    const float* loww  = (const float*)d_in[6];
    const float* highw = (const float*)d_in[7];
    float* out = (float*)d_out;

    // ws layout ~57.5 MB (< proven 62.4): q,t1,t2,tv fp32 planar; wtab bf16
    float* ws   = (float*)d_ws;
    float* q    = ws;                          // C*HW
    float* t1   = q  + (size_t)C * HW;         // C*HW
    float* t2   = t1 + (size_t)C * HW;         // C*HW
    float* tv   = t2 + (size_t)C * HW;         // C*HW
    u16*   wtab = (u16*)(tv + (size_t)C * HW); // 25*HW bf16
    float* msum = (float*)(wtab + (size_t)25 * HW);  // HW
    float* M1   = msum + HW;                   // C*C
    float* M2   = M1 + C * C;                  // C*C

    dim3 blk(256);
    dim3 gpix(HW / 256);                 // 576
    dim3 gvec((C * HW / 4) / 256);       // 3024 (C*HW divisible by 1024)
    dim3 gmat((C * C + 255) / 256);

    k_prep<<<gpix, blk, 0, stream>>>(un, rgb, sp, q, wtab, msum);
    k_mats<<<gmat, blk, 0, stream>>>(Wsp, Wbi, Cm, M1, M2);

    for (int it = 0; it < 5; it++) {
        k_S<<<gpix, blk, 0, stream>>>(q, M1, M2, t1, t2);
        k_V<<<gvec, blk, 0, stream>>>(t1, tv);
        k_F<<<gvec, blk, 0, stream>>>(tv, t2, wtab, msum, un, loww, highw, q);
    }
    k_store<<<gpix, blk, 0, stream>>>(q, out);
}

// Round 10
// 372.107 us; speedup vs baseline: 1.8825x; 1.2550x over previous
//
#include <hip/hip_runtime.h>
#include <hip/hip_bf16.h>

static constexpr int C  = 21;
static constexpr int H  = 384;
static constexpr int W  = 384;
static constexpr int HW = H * W;
static constexpr float NCLIQ = 5.0f;

typedef unsigned short u16;

// function-local constexpr taps: exp(-o^2/18), o=-6..6 — folds to immediates
#define GKDEF constexpr float gk[13] = { \
    0.13533528f, 0.24935222f, 0.41111229f, 0.60653066f, 0.80073740f, \
    0.94595947f, 1.00000000f, 0.94595947f, 0.80073740f, 0.60653066f, \
    0.41111229f, 0.24935222f, 0.13533528f }

__device__ __forceinline__ float bfu2f(u16 u) {
    return __uint_as_float(((unsigned)u) << 16);
}
__device__ __forceinline__ u16 f2bfu(float f) {
    unsigned x = __float_as_uint(f);
    return (u16)((x + 0x7FFF + ((x >> 16) & 1)) >> 16);   // RNE; inputs finite
}

// ---- prep: q init + wtab (bf16) + msum + precomputed inverse norms ---------
__global__ __launch_bounds__(256)
void k_prep(const float* __restrict__ un, const float* __restrict__ rgb,
            const int* __restrict__ sp,
            float* __restrict__ q, u16* __restrict__ wtab,
            float* __restrict__ msum, float* __restrict__ inv_sp,
            float* __restrict__ inv_bn) {
    GKDEF;
    int p = blockIdx.x * 256 + threadIdx.x;     // HW % 256 == 0
    int y = p / W, x = p - y * W;

    for (int c = 0; c < C; c++) q[c * HW + p] = un[p * C + c];

    // bilateral weights (bf16-rounded); denominator uses the SAME rounded
    // values so numerator/denominator stay consistent
    float r0 = rgb[p * 3 + 0];
    float g0 = rgb[p * 3 + 1];
    float b0 = rgb[p * 3 + 2];
    float s = 0.f;
    int t = 0;
    for (int dy = -2; dy <= 2; dy++) {
        for (int dx = -2; dx <= 2; dx++, t++) {
            int sy = y - dy, sx = x - dx;
            float wv = 0.f;
            if (sy >= 0 && sy < H && sx >= 0 && sx < W) {
                int o = sy * W + sx;
                float dr = r0 - rgb[o * 3 + 0];
                float dg = g0 - rgb[o * 3 + 1];
                float db = b0 - rgb[o * 3 + 2];
                wv = expf(-(float)(dy * dy + dx * dx) * (1.0f / 51200.0f)) *
                     expf(-(dr * dr + dg * dg + db * db) * (1.0f / 18.0f));
            }
            u16 wu = f2bfu(wv);
            wtab[(size_t)t * HW + p] = wu;
            s += bfu2f(wu);
        }
    }
    inv_bn[p] = 1.0f / s;    // s >= 1 (center tap)

    // separable spatial norm 1/(fy*fx)
    float fy = 0.f, fx = 0.f;
    for (int o = -6; o <= 6; o++) {
        if (y - o >= 0 && y - o < H) fy += gk[o + 6];
        if (x - o >= 0 && x - o < W) fx += gk[o + 6];
    }
    inv_sp[p] = 1.0f / (fy * fx);

    int vv = sp[x * W + y];   // sp_map is transposed: sp[x][y]
    msum[p] = (vv == 5 || vv == 37 || vv == 81 || vv == 150 || vv == 230) ? 1.0f : 0.0f;
}

// M1 = Cm @ Ws,  M2 = Cm @ Wb
__global__ void k_mats(const float* __restrict__ Wsp, const float* __restrict__ Wbi,
                       const float* __restrict__ Cm,
                       float* __restrict__ M1, float* __restrict__ M2) {
    int i = blockIdx.x * blockDim.x + threadIdx.x;
    if (i >= C * C) return;
    int c = i / C, k = i - c * C;
    float a1 = 0.f, a2 = 0.f;
    for (int j = 0; j < C; j++) {
        float cm = Cm[c * C + j];
        a1 += cm * Wsp[j * C + k];
        a2 += cm * Wbi[j * C + k];
    }
    M1[i] = a1;
    M2[i] = a2;
}

// softmax(q) -> sm  (1 px/thread; small register footprint)
__global__ __launch_bounds__(256)
void k_sm(const float* __restrict__ q, float* __restrict__ sm) {
    int p = blockIdx.x * 256 + threadIdx.x;
    float v[C];
    float mx = -1e30f;
    for (int c = 0; c < C; c++) {
        v[c] = q[c * HW + p];
        mx = fmaxf(mx, v[c]);
    }
    float s = 0.f;
    for (int c = 0; c < C; c++) {
        v[c] = expf(v[c] - mx);
        s += v[c];
    }
    float inv = 1.0f / s;
    for (int c = 0; c < C; c++) sm[c * HW + p] = v[c] * inv;
}

// t1 = M1@sm, t2 = M2@sm — channel-parallel, 4 px/thread, float4; M rows in LDS
__global__ __launch_bounds__(256)
void k_T(const float* __restrict__ sm, const float* __restrict__ M1,
         const float* __restrict__ M2,
         float* __restrict__ t1, float* __restrict__ t2) {
    __shared__ float m1r[C], m2r[C];
    int c = blockIdx.y;
    if (threadIdx.x < C) {
        m1r[threadIdx.x] = M1[c * C + threadIdx.x];
        m2r[threadIdx.x] = M2[c * C + threadIdx.x];
    }
    __syncthreads();
    int p4 = (blockIdx.x * 256 + threadIdx.x) * 4;
    float a1x = 0.f, a1y = 0.f, a1z = 0.f, a1w = 0.f;
    float a2x = 0.f, a2y = 0.f, a2z = 0.f, a2w = 0.f;
    for (int k = 0; k < C; k++) {
        float4 sv = *(const float4*)(sm + (size_t)k * HW + p4);
        float w1 = m1r[k], w2 = m2r[k];
        a1x += w1 * sv.x; a1y += w1 * sv.y; a1z += w1 * sv.z; a1w += w1 * sv.w;
        a2x += w2 * sv.x; a2y += w2 * sv.y; a2z += w2 * sv.z; a2w += w2 * sv.w;
    }
    float4 r1; r1.x = a1x; r1.y = a1y; r1.z = a1z; r1.w = a1w;
    float4 r2; r2.x = a2x; r2.y = a2y; r2.z = a2z; r2.w = a2w;
    *(float4*)(t1 + (size_t)c * HW + p4) = r1;
    *(float4*)(t2 + (size_t)c * HW + p4) = r2;
}

// fused separable blur (LDS-tiled) + bilateral + update. One channel per
// block-z; 128x8 output tile; 256 threads, 4 px/thread.
__global__ __launch_bounds__(256)
void k_VF(const float* __restrict__ t1, const float* __restrict__ t2,
          const u16* __restrict__ wtab, const float* __restrict__ msum,
          const float* __restrict__ inv_sp, const float* __restrict__ inv_bn,
          const float* __restrict__ un,
          const float* __restrict__ loww, const float* __restrict__ highw,
          float* __restrict__ q) {
    GKDEF;
    __shared__ float A[20 * 144];   // t1 halo tile: rows y0-6..y0+13, cols x0-8..x0+135
    __shared__ float B[8 * 144];    // blurV output
    int c  = blockIdx.z;
    int x0 = blockIdx.x * 128;
    int y0 = blockIdx.y * 8;
    const float* t1p = t1 + (size_t)c * HW;

    // ---- stage A (zero-padded) ----
    for (int i = threadIdx.x; i < 20 * 36; i += 256) {
        int r = i / 36, q4 = i - r * 36;
        int gy = y0 - 6 + r;
        int gx = x0 - 8 + q4 * 4;
        float4 v;
        if (gy < 0 || gy >= H) {
            v.x = v.y = v.z = v.w = 0.f;
        } else if (gx >= 0 && gx + 3 < W) {
            v = *(const float4*)(t1p + gy * W + gx);
        } else {
            float e[4];
            for (int j = 0; j < 4; j++) {
                int xx = gx + j;
                e[j] = (xx >= 0 && xx < W) ? t1p[gy * W + xx] : 0.f;
            }
            v.x = e[0]; v.y = e[1]; v.z = e[2]; v.w = e[3];
        }
        *(float4*)(A + r * 144 + q4 * 4) = v;
    }
    __syncthreads();

    // ---- blurV: B[r][col] = sum_d gk[d] * A[r+d][col]  (gk symmetric) ----
    for (int i = threadIdx.x; i < 8 * 144; i += 256) {
        int r = i / 144, col = i - r * 144;
        float a = 0.f;
        for (int d = 0; d < 13; d++) a += gk[d] * A[(r + d) * 144 + col];
        B[i] = a;
    }
    __syncthreads();

    // ---- per-thread: 4 consecutive x of one row ----
    int row = threadIdx.x >> 5;            // 0..7
    int xq  = (threadIdx.x & 31) * 4;      // 0..124
    int y   = y0 + row;
    int x4  = x0 + xq;
    int p4  = y * W + x4;

    // horizontal 13-tap from LDS B (window of 16)
    float bw[16];
    for (int i = 0; i < 16; i++) bw[i] = B[row * 144 + xq + 2 + i];
    float sp_[4];
    for (int j = 0; j < 4; j++) {
        float a = 0.f;
        for (int t = 0; t < 13; t++) a += gk[t] * bw[j + t];
        sp_[j] = a;
    }

    // bilateral over t2 (weights bf16; OOB taps have weight 0)
    float bi[4] = {0.f, 0.f, 0.f, 0.f};
    const float* t2p = t2 + (size_t)c * HW;
    int t = 0;
    for (int dy = -2; dy <= 2; dy++) {
        int sy = min(max(y - dy, 0), H - 1);    // clamped; OOB rows weight 0
        const float* rowp = t2p + sy * W;
        float r[12];
        for (int i = 0; i < 3; i++) {
            int bx = x4 - 4 + 4 * i;
            int bc = min(max(bx, 0), W - 4);    // clamped; OOB cols weight 0
            float4 vv = *(const float4*)(rowp + bc);
            r[4 * i + 0] = vv.x; r[4 * i + 1] = vv.y;
            r[4 * i + 2] = vv.z; r[4 * i + 3] = vv.w;
        }
        for (int dx = -2; dx <= 2; dx++, t++) {
            ushort4 wu = *(const ushort4*)(wtab + (size_t)t * HW + p4);
            bi[0] += bfu2f(wu.x) * r[0 - dx + 4];
            bi[1] += bfu2f(wu.y) * r[1 - dx + 4];
            bi[2] += bfu2f(wu.z) * r[2 - dx + 4];
            bi[3] += bfu2f(wu.w) * r[3 - dx + 4];
        }
    }

    // update: q = un - pairwise + superpixel closed form
    float lc = loww[c], hw_ = highw[0];
    float4 msv = *(const float4*)(msum + p4);
    float4 isv = *(const float4*)(inv_sp + p4);
    float4 ibv = *(const float4*)(inv_bn + p4);
    float* qp = q + (size_t)c * HW + p4;
    float4 qo4 = *(const float4*)qp;
    float msa[4] = {msv.x, msv.y, msv.z, msv.w};
    float isa[4] = {isv.x, isv.y, isv.z, isv.w};
    float iba[4] = {ibv.x, ibv.y, ibv.z, ibv.w};
    float qoa[4] = {qo4.x, qo4.y, qo4.z, qo4.w};
    float outv[4];
    for (int j = 0; j < 4; j++) {
        float pw = sp_[j] * isa[j] + bi[j] * iba[j];
        float qo = qoa[j];
        float ft = (msa[j] * qo + (NCLIQ - msa[j])) / qo;
        float su = lc * ft + hw_ * (1.0f - ft);
        outv[j] = un[(p4 + j) * C + c] - pw + su;
    }
    float4 res; res.x = outv[0]; res.y = outv[1]; res.z = outv[2]; res.w = outv[3];
    *(float4*)qp = res;
}

// final transpose: q (C,H,W) -> out (H,W,C), LDS-staged
__global__ __launch_bounds__(256)
void k_store(const float* __restrict__ q, float* __restrict__ out) {
    __shared__ float l[256 * C];
    int p0 = blockIdx.x * 256;
    for (int c = 0; c < C; c++)
        l[threadIdx.x * C + c] = q[c * HW + p0 + threadIdx.x];
    __syncthreads();
    float* dst = out + (size_t)p0 * C;
    for (int i = threadIdx.x; i < 256 * C; i += 256) dst[i] = l[i];
}

// ---- launch -----------------------------------------------------------------

extern "C" void kernel_launch(void* const* d_in, const int* in_sizes, int n_in,
                              void* d_out, int out_size, void* d_ws, size_t ws_size,
                              hipStream_t stream) {
    const float* un    = (const float*)d_in[0];
    const float* rgb   = (const float*)d_in[1];
    const int*   sp    = (const int*)d_in[2];
    const float* Wsp   = (const float*)d_in[3];
    const float* Wbi   = (const float*)d_in[4];
    const float* Cm    = (const float*)d_in[5];
    const float* loww  = (const float*)d_in[6];
    const float* highw = (const float*)d_in[7];
    float* out = (float*)d_out;

    // ws layout ~58.7 MB (< proven 62.4)
    float* ws    = (float*)d_ws;
    float* q     = ws;                          // C*HW
    float* smb   = q   + (size_t)C * HW;        // C*HW
    float* t1    = smb + (size_t)C * HW;        // C*HW
    float* t2    = t1  + (size_t)C * HW;        // C*HW
    u16*   wtab  = (u16*)(t2 + (size_t)C * HW); // 25*HW bf16
    float* msum  = (float*)(wtab + (size_t)25 * HW);  // HW
    float* isp   = msum + HW;                   // HW
    float* ibn   = isp + HW;                    // HW
    float* M1    = ibn + HW;                    // C*C
    float* M2    = M1 + C * C;                  // C*C

    dim3 blk(256);
    dim3 gpix(HW / 256);                 // 576
    dim3 gT(HW / 4 / 256, C);            // 144 x 21
    dim3 gVF(W / 128, H / 8, C);         // 3 x 48 x 21
    dim3 gmat((C * C + 255) / 256);

    k_prep<<<gpix, blk, 0, stream>>>(un, rgb, sp, q, wtab, msum, isp, ibn);
    k_mats<<<gmat, blk, 0, stream>>>(Wsp, Wbi, Cm, M1, M2);

    for (int it = 0; it < 5; it++) {
        k_sm<<<gpix, blk, 0, stream>>>(q, smb);
        k_T<<<gT, blk, 0, stream>>>(smb, M1, M2, t1, t2);
        k_VF<<<gVF, blk, 0, stream>>>(t1, t2, wtab, msum, isp, ibn,
                                      un, loww, highw, q);
    }
    k_store<<<gpix, blk, 0, stream>>>(q, out);
}

// Round 11
// 302.624 us; speedup vs baseline: 2.3147x; 1.2296x over previous
//
#include <hip/hip_runtime.h>
#include <hip/hip_bf16.h>

static constexpr int C  = 21;
static constexpr int H  = 384;
static constexpr int W  = 384;
static constexpr int HW = H * W;
static constexpr float NCLIQ = 5.0f;

typedef unsigned short u16;

// function-local constexpr taps: exp(-o^2/18), o=-6..6 — folds to immediates
#define GKDEF constexpr float gk[13] = { \
    0.13533528f, 0.24935222f, 0.41111229f, 0.60653066f, 0.80073740f, \
    0.94595947f, 1.00000000f, 0.94595947f, 0.80073740f, 0.60653066f, \
    0.41111229f, 0.24935222f, 0.13533528f }

__device__ __forceinline__ float bfu2f(u16 u) {
    return __uint_as_float(((unsigned)u) << 16);
}
__device__ __forceinline__ u16 f2bfu(float f) {
    unsigned x = __float_as_uint(f);
    return (u16)((x + 0x7FFF + ((x >> 16) & 1)) >> 16);   // RNE; inputs finite
}

// ---- prep: q/un planar init + wtab (bf16) + msum + inverse norms ----------
__global__ __launch_bounds__(256)
void k_prep(const float* __restrict__ un, const float* __restrict__ rgb,
            const int* __restrict__ sp,
            float* __restrict__ q, float* __restrict__ unp,
            u16* __restrict__ wtab, float* __restrict__ msum,
            float* __restrict__ inv_sp, float* __restrict__ inv_bn) {
    GKDEF;
    int p = blockIdx.x * 256 + threadIdx.x;     // HW % 256 == 0
    int y = p / W, x = p - y * W;

    for (int c = 0; c < C; c++) {
        float v = un[p * C + c];
        q[c * HW + p] = v;
        unp[c * HW + p] = v;
    }

    // bilateral weights (bf16-rounded); denominator uses the SAME rounded
    // values so numerator/denominator stay consistent
    float r0 = rgb[p * 3 + 0];
    float g0 = rgb[p * 3 + 1];
    float b0 = rgb[p * 3 + 2];
    float s = 0.f;
    int t = 0;
    for (int dy = -2; dy <= 2; dy++) {
        for (int dx = -2; dx <= 2; dx++, t++) {
            int sy = y - dy, sx = x - dx;
            float wv = 0.f;
            if (sy >= 0 && sy < H && sx >= 0 && sx < W) {
                int o = sy * W + sx;
                float dr = r0 - rgb[o * 3 + 0];
                float dg = g0 - rgb[o * 3 + 1];
                float db = b0 - rgb[o * 3 + 2];
                wv = expf(-(float)(dy * dy + dx * dx) * (1.0f / 51200.0f)) *
                     expf(-(dr * dr + dg * dg + db * db) * (1.0f / 18.0f));
            }
            u16 wu = f2bfu(wv);
            wtab[(size_t)t * HW + p] = wu;
            s += bfu2f(wu);
        }
    }
    inv_bn[p] = 1.0f / s;    // s >= 1 (center tap)

    float fy = 0.f, fx = 0.f;
    for (int o = -6; o <= 6; o++) {
        if (y - o >= 0 && y - o < H) fy += gk[o + 6];
        if (x - o >= 0 && x - o < W) fx += gk[o + 6];
    }
    inv_sp[p] = 1.0f / (fy * fx);

    int vv = sp[x * W + y];   // sp_map is transposed: sp[x][y]
    msum[p] = (vv == 5 || vv == 37 || vv == 81 || vv == 150 || vv == 230) ? 1.0f : 0.0f;
}

// M1 = Cm @ Ws,  M2 = Cm @ Wb
__global__ void k_mats(const float* __restrict__ Wsp, const float* __restrict__ Wbi,
                       const float* __restrict__ Cm,
                       float* __restrict__ M1, float* __restrict__ M2) {
    int i = blockIdx.x * blockDim.x + threadIdx.x;
    if (i >= C * C) return;
    int c = i / C, k = i - c * C;
    float a1 = 0.f, a2 = 0.f;
    for (int j = 0; j < C; j++) {
        float cm = Cm[c * C + j];
        a1 += cm * Wsp[j * C + k];
        a2 += cm * Wbi[j * C + k];
    }
    M1[i] = a1;
    M2[i] = a2;
}

// fused softmax + both 21x21 matmuls, pixel-parallel.
// M1/M2 read via thread-uniform indices -> scalar loads (SGPR operands),
// no LDS staging. 1/s folded into the output scale. Outputs bf16.
__global__ __launch_bounds__(256)
void k_ST(const float* __restrict__ q, const float* __restrict__ M1,
          const float* __restrict__ M2,
          u16* __restrict__ t1, u16* __restrict__ t2) {
    int p = blockIdx.x * 256 + threadIdx.x;
    float v[C];
    float mx = -1e30f;
#pragma unroll
    for (int c = 0; c < C; c++) {
        v[c] = q[c * HW + p];
        mx = fmaxf(mx, v[c]);
    }
    float s = 0.f;
#pragma unroll
    for (int c = 0; c < C; c++) {
        v[c] = expf(v[c] - mx);
        s += v[c];
    }
    float inv = 1.0f / s;
    float a1[C], a2[C];
#pragma unroll
    for (int c = 0; c < C; c++) { a1[c] = 0.f; a2[c] = 0.f; }
#pragma unroll
    for (int k = 0; k < C; k++) {
        float e = v[k];
#pragma unroll
        for (int c = 0; c < C; c++) {
            a1[c] += M1[c * C + k] * e;   // uniform index -> s_load
            a2[c] += M2[c * C + k] * e;
        }
    }
#pragma unroll
    for (int c = 0; c < C; c++) {
        t1[c * HW + p] = f2bfu(a1[c] * inv);
        t2[c * HW + p] = f2bfu(a2[c] * inv);
    }
}

// fused separable blur (LDS-tiled) + bilateral + update. One channel per
// block-z; 128x8 output tile; 256 threads, 4 px/thread. t1/t2 are bf16.
__global__ __launch_bounds__(256)
void k_VF(const u16* __restrict__ t1, const u16* __restrict__ t2,
          const u16* __restrict__ wtab, const float* __restrict__ msum,
          const float* __restrict__ inv_sp, const float* __restrict__ inv_bn,
          const float* __restrict__ unp,
          const float* __restrict__ loww, const float* __restrict__ highw,
          float* __restrict__ q) {
    GKDEF;
    __shared__ float A[20 * 144];   // t1 halo tile (fp32 in LDS)
    __shared__ float B[8 * 144];    // blurV output
    int c  = blockIdx.z;
    int x0 = blockIdx.x * 128;
    int y0 = blockIdx.y * 8;
    const u16* t1p = t1 + (size_t)c * HW;

    // ---- stage A (zero-padded), bf16 -> fp32 ----
    for (int i = threadIdx.x; i < 20 * 36; i += 256) {
        int r = i / 36, q4 = i - r * 36;
        int gy = y0 - 6 + r;
        int gx = x0 - 8 + q4 * 4;     // 4-aligned
        float4 v;
        if (gy < 0 || gy >= H) {
            v.x = v.y = v.z = v.w = 0.f;
        } else if (gx >= 0 && gx + 3 < W) {
            ushort4 u = *(const ushort4*)(t1p + gy * W + gx);
            v.x = bfu2f(u.x); v.y = bfu2f(u.y); v.z = bfu2f(u.z); v.w = bfu2f(u.w);
        } else {
            float e[4];
            for (int j = 0; j < 4; j++) {
                int xx = gx + j;
                e[j] = (xx >= 0 && xx < W) ? bfu2f(t1p[gy * W + xx]) : 0.f;
            }
            v.x = e[0]; v.y = e[1]; v.z = e[2]; v.w = e[3];
        }
        *(float4*)(A + r * 144 + q4 * 4) = v;
    }
    __syncthreads();

    // ---- blurV: B[r][col] = sum_d gk[d] * A[r+d][col] ----
    for (int i = threadIdx.x; i < 8 * 144; i += 256) {
        int r = i / 144, col = i - r * 144;
        float a = 0.f;
        for (int d = 0; d < 13; d++) a += gk[d] * A[(r + d) * 144 + col];
        B[i] = a;
    }
    __syncthreads();

    // ---- per-thread: 4 consecutive x of one row ----
    int row = threadIdx.x >> 5;            // 0..7
    int xq  = (threadIdx.x & 31) * 4;      // 0..124
    int y   = y0 + row;
    int x4  = x0 + xq;
    int p4  = y * W + x4;

    // horizontal 13-tap from LDS B
    float bw[16];
    for (int i = 0; i < 16; i++) bw[i] = B[row * 144 + xq + 2 + i];
    float sp_[4];
    for (int j = 0; j < 4; j++) {
        float a = 0.f;
        for (int t = 0; t < 13; t++) a += gk[t] * bw[j + t];
        sp_[j] = a;
    }

    // bilateral over t2 (bf16; OOB taps carry weight 0)
    float bi[4] = {0.f, 0.f, 0.f, 0.f};
    const u16* t2p = t2 + (size_t)c * HW;
    int t = 0;
    for (int dy = -2; dy <= 2; dy++) {
        int sy = min(max(y - dy, 0), H - 1);    // clamped; OOB rows weight 0
        const u16* rowp = t2p + sy * W;
        float r[12];
        for (int i = 0; i < 3; i++) {
            int bx = x4 - 4 + 4 * i;
            int bc = min(max(bx, 0), W - 4);    // clamped; OOB cols weight 0
            ushort4 u = *(const ushort4*)(rowp + bc);
            r[4 * i + 0] = bfu2f(u.x); r[4 * i + 1] = bfu2f(u.y);
            r[4 * i + 2] = bfu2f(u.z); r[4 * i + 3] = bfu2f(u.w);
        }
        for (int dx = -2; dx <= 2; dx++, t++) {
            ushort4 wu = *(const ushort4*)(wtab + (size_t)t * HW + p4);
            bi[0] += bfu2f(wu.x) * r[0 - dx + 4];
            bi[1] += bfu2f(wu.y) * r[1 - dx + 4];
            bi[2] += bfu2f(wu.z) * r[2 - dx + 4];
            bi[3] += bfu2f(wu.w) * r[3 - dx + 4];
        }
    }

    // update: q = un - pairwise + superpixel closed form (planar un, float4)
    float lc = loww[c], hw_ = highw[0];
    float4 msv = *(const float4*)(msum + p4);
    float4 isv = *(const float4*)(inv_sp + p4);
    float4 ibv = *(const float4*)(inv_bn + p4);
    float4 unv = *(const float4*)(unp + (size_t)c * HW + p4);
    float* qp = q + (size_t)c * HW + p4;
    float4 qo4 = *(const float4*)qp;
    float msa[4] = {msv.x, msv.y, msv.z, msv.w};
    float isa[4] = {isv.x, isv.y, isv.z, isv.w};
    float iba[4] = {ibv.x, ibv.y, ibv.z, ibv.w};
    float qoa[4] = {qo4.x, qo4.y, qo4.z, qo4.w};
    float una[4] = {unv.x, unv.y, unv.z, unv.w};
    float outv[4];
    for (int j = 0; j < 4; j++) {
        float pw = sp_[j] * isa[j] + bi[j] * iba[j];
        float qo = qoa[j];
        float ft = (msa[j] * qo + (NCLIQ - msa[j])) / qo;
        float su = lc * ft + hw_ * (1.0f - ft);
        outv[j] = una[j] - pw + su;
    }
    float4 res; res.x = outv[0]; res.y = outv[1]; res.z = outv[2]; res.w = outv[3];
    *(float4*)qp = res;
}

// final transpose: q (C,H,W) -> out (H,W,C), LDS-staged
__global__ __launch_bounds__(256)
void k_store(const float* __restrict__ q, float* __restrict__ out) {
    __shared__ float l[256 * C];
    int p0 = blockIdx.x * 256;
    for (int c = 0; c < C; c++)
        l[threadIdx.x * C + c] = q[c * HW + p0 + threadIdx.x];
    __syncthreads();
    float* dst = out + (size_t)p0 * C;
    for (int i = threadIdx.x; i < 256 * C; i += 256) dst[i] = l[i];
}

// ---- launch -----------------------------------------------------------------

extern "C" void kernel_launch(void* const* d_in, const int* in_sizes, int n_in,
                              void* d_out, int out_size, void* d_ws, size_t ws_size,
                              hipStream_t stream) {
    const float* un    = (const float*)d_in[0];
    const float* rgb   = (const float*)d_in[1];
    const int*   sp    = (const int*)d_in[2];
    const float* Wsp   = (const float*)d_in[3];
    const float* Wbi   = (const float*)d_in[4];
    const float* Cm    = (const float*)d_in[5];
    const float* loww  = (const float*)d_in[6];
    const float* highw = (const float*)d_in[7];
    float* out = (float*)d_out;

    // ws layout ~46.5 MB (ws_size is 256 MiB per harness fill WRITE_SIZE)
    float* ws    = (float*)d_ws;
    float* q     = ws;                            // C*HW fp32
    float* unp   = q   + (size_t)C * HW;          // C*HW fp32
    float* msum  = unp + (size_t)C * HW;          // HW
    float* isp   = msum + HW;                     // HW
    float* ibn   = isp + HW;                      // HW
    float* M1    = ibn + HW;                      // C*C
    float* M2    = M1 + C * C;                    // C*C
    u16*   t1    = (u16*)(M2 + C * C + 6);        // C*HW bf16 (offset keeps 16B align)
    u16*   t2    = t1 + (size_t)C * HW;           // C*HW bf16
    u16*   wtab  = t2 + (size_t)C * HW;           // 25*HW bf16

    dim3 blk(256);
    dim3 gpix(HW / 256);                 // 576
    dim3 gVF(W / 128, H / 8, C);         // 3 x 48 x 21
    dim3 gmat((C * C + 255) / 256);

    k_prep<<<gpix, blk, 0, stream>>>(un, rgb, sp, q, unp, wtab, msum, isp, ibn);
    k_mats<<<gmat, blk, 0, stream>>>(Wsp, Wbi, Cm, M1, M2);

    for (int it = 0; it < 5; it++) {
        k_ST<<<gpix, blk, 0, stream>>>(q, M1, M2, t1, t2);
        k_VF<<<gVF, blk, 0, stream>>>(t1, t2, wtab, msum, isp, ibn,
                                      unp, loww, highw, q);
    }
    k_store<<<gpix, blk, 0, stream>>>(q, out);
}